// Round 10
// baseline (203.365 us; speedup 1.0000x reference)
//
#include <hip/hip_runtime.h>
#include <stdint.h>

#define AS1 __attribute__((address_space(1)))
#define AS3 __attribute__((address_space(3)))

typedef _Float16 f16;
typedef _Float16 f16x8 __attribute__((ext_vector_type(8)));
typedef _Float16 f16x4 __attribute__((ext_vector_type(4)));
typedef float    f32x4  __attribute__((ext_vector_type(4)));
typedef float    f32x16 __attribute__((ext_vector_type(16)));
typedef uint32_t u32x4  __attribute__((ext_vector_type(4)));
typedef uint32_t u32x2  __attribute__((ext_vector_type(2)));

#define B_  4
#define T_  2048
#define C_  768
#define H_  12
#define D_  64
#define M_  (B_*T_)      /* 8192 */
#define N1_ (3*C_)       /* 2304 */

__device__ __forceinline__ void g2l16(const void* g, void* l) {
  __builtin_amdgcn_global_load_lds((const AS1 void*)g, (AS3 void*)l, 16, 0, 0);
}

__device__ __forceinline__ f32x4 fzero4() { f32x4 z = {0.f, 0.f, 0.f, 0.f}; return z; }

__device__ __forceinline__ uint32_t pk_u32(float a, float b) {
  auto t = __builtin_amdgcn_cvt_pkrtz(a, b);  // 2 x f16 packed in 32 bits
  return *(uint32_t*)&t;
}

// permlane32_swap: new_d[l<32]=old_d[l], new_d[l>=32]=old_s[l-32];
//                  new_s[l<32]=old_d[l+32], new_s[l>=32]=old_s[l].
__device__ __forceinline__ void pl32swap(uint32_t& d, uint32_t& s) {
  u32x2 r = __builtin_amdgcn_permlane32_swap(d, s, false, false);
  d = r[0]; s = r[1];
}

// ------------- fused prep: Wqkv^T cvt | Wo^T cvt | x cvt | idx/cnt init -------------
__global__ __launch_bounds__(256)
void prep_kernel(const float* __restrict__ Wqkv, f16* __restrict__ WqkvT,
                 const float* __restrict__ Wo, f16* __restrict__ WoT,
                 const float* __restrict__ x, f16* __restrict__ xh,
                 int* __restrict__ idx, int* __restrict__ cnt) {
  __shared__ float tile[32][33];
  const int blk = blockIdx.x;
  if (blk < 2304) {
    const float* in; f16* out; int R, C, bx, by;
    if (blk < 1728) { in = Wqkv; out = WqkvT; R = 768; C = 2304; bx = blk % 72; by = blk / 72; }
    else { const int k = blk - 1728; in = Wo; out = WoT; R = 768; C = 768; bx = k % 24; by = k / 24; }
    const int tx = threadIdx.x & 31, ty = threadIdx.x >> 5;
    const int c0 = bx * 32, r0 = by * 32;
#pragma unroll
    for (int i = 0; i < 32; i += 8)
      tile[ty + i][tx] = in[(long)(r0 + ty + i) * C + c0 + tx];
    __syncthreads();
#pragma unroll
    for (int i = 0; i < 32; i += 8)
      out[(long)(c0 + ty + i) * R + r0 + tx] = (f16)tile[tx][ty + i];
  } else if (blk < 8448) {
    const int i = ((blk - 2304) * 256 + threadIdx.x) * 4;
    const float4 v = *(const float4*)(x + i);
    f16x4 o = {(f16)v.x, (f16)v.y, (f16)v.z, (f16)v.w};
    *(f16x4*)(xh + i) = o;
  } else {
    const int g = (blk - 8448) * 256 + threadIdx.x;
    idx[g] = 0;           // pad entries point at row 0 (valid; killed by key>=nk C-init)
    if (g < B_) cnt[g] = 0;
  }
}

// ------------- mask compaction: idx[b][slot]=t for kept keys (mask==0) -------------
__global__ __launch_bounds__(256)
void compact_kernel(const int* __restrict__ mask, int* __restrict__ idx,
                    int* __restrict__ cnt) {
  const int b = blockIdx.y;
  const int t = blockIdx.x * 256 + threadIdx.x;
  if (mask[b * T_ + t] == 0) {                 // keep where mask==0 (module quirk)
    const int s = atomicAdd(&cnt[b], 1);       // device-scope
    idx[b * T_ + s] = t;
  }
}

// ------- Wo GEMM (r7-proven): 128x128xBK32, 2-phase dbuf, jj^((r>>1)&3) swizzle -------
template <typename OutT>
__global__ __launch_bounds__(256)
void gemm_bias_kernel(const f16* __restrict__ A, const f16* __restrict__ Bt,
                      const float* __restrict__ bias, OutT* __restrict__ Cc,
                      int K, int ldc) {
  __shared__ f16 lA[2 * 128 * 32];
  __shared__ f16 lB[2 * 128 * 32];
  const int tid = threadIdx.x;
  const int n0 = blockIdx.x * 128, m0 = blockIdx.y * 128;
  const int lane = tid & 63, w = tid >> 6;
  const int wm = (w & 1) * 64, wn = (w >> 1) * 64;
  const int r15 = lane & 15, q4 = lane >> 4;
  const int rkey = (r15 >> 1) & 3;             // read-side swizzle key

  const int r0 = tid >> 2, jj = tid & 3;
  const int scol = (jj ^ ((r0 >> 1) & 3)) * 8; // f16 units, same for i=0,1
  const f16* pA0 = A + (long)(m0 + r0) * K + scol;
  const f16* pB0 = Bt + (long)(n0 + r0) * K + scol;
  const long rstep = (long)64 * K;             // i=1 rows are +64

  f32x4 acc[4][4];
#pragma unroll
  for (int i = 0; i < 4; i++)
#pragma unroll
    for (int j = 0; j < 4; j++) acc[i][j] = fzero4();

#define STAGE_WO(bufsel, kb) do {                                   \
  const int lb = (bufsel) * 4096;                                   \
  g2l16(pA0 + (kb), &lA[lb + tid * 8]);                             \
  g2l16(pA0 + rstep + (kb), &lA[lb + 2048 + tid * 8]);              \
  g2l16(pB0 + (kb), &lB[lb + tid * 8]);                             \
  g2l16(pB0 + rstep + (kb), &lB[lb + 2048 + tid * 8]);              \
} while (0)

#define COMPUTE_WO(bufsel) do {                                     \
  const int lb = (bufsel) * 4096;                                   \
  const int cofs = (q4 ^ rkey) * 8;                                 \
  f16x8 af[4], bfv[4];                                              \
  _Pragma("unroll")                                                 \
  for (int mi = 0; mi < 4; mi++)                                    \
    af[mi] = *(const f16x8*)&lA[lb + (wm + mi * 16 + r15) * 32 + cofs]; \
  _Pragma("unroll")                                                 \
  for (int ni = 0; ni < 4; ni++)                                    \
    bfv[ni] = *(const f16x8*)&lB[lb + (wn + ni * 16 + r15) * 32 + cofs]; \
  _Pragma("unroll")                                                 \
  for (int mi = 0; mi < 4; mi++)                                    \
    _Pragma("unroll")                                               \
    for (int ni = 0; ni < 4; ni++)                                  \
      acc[mi][ni] = __builtin_amdgcn_mfma_f32_16x16x32_f16(af[mi], bfv[ni], acc[mi][ni], 0, 0, 0); \
} while (0)

  STAGE_WO(0, 0);
  __syncthreads();

  int cur = 0;
  const int NT = K / 32;                 // 24
  for (int t = 0; t < NT - 1; t++) {
    STAGE_WO(cur ^ 1, (t + 1) * 32);     // issue next-tile loads FIRST
    COMPUTE_WO(cur);                     // ds_read + MFMA hide the load flight
    __syncthreads();                     // one drain+barrier per K-tile
    cur ^= 1;
  }
  COMPUTE_WO(cur);

#undef STAGE_WO
#undef COMPUTE_WO

#pragma unroll
  for (int ni = 0; ni < 4; ni++) {
    const int col = n0 + wn + ni * 16 + r15;
    const float bs = bias[col];
#pragma unroll
    for (int mi = 0; mi < 4; mi++) {
#pragma unroll
      for (int r = 0; r < 4; r++) {
        const int row = m0 + wm + mi * 16 + q4 * 4 + r;
        Cc[(long)row * ldc + col] = (OutT)(acc[mi][ni][r] + bs);
      }
    }
  }
}

// ------- fused masked QKV GEMM v4: r9 structure + XCD-aware block remap (T1).
// r9 counters: FETCH 51MB vs ~16MB working set, HBM 2.0TB/s -> A row-panels
// re-fetched ~4x because the 18 blocks sharing one A-panel (same mb) round-robin
// across all 8 XCD L2s (x-fastest dispatch). Remap (bijective over 1152 blocks):
//   g = y*18 + x; xcd = g&7; local = g>>3 (0..143);
//   nb = local%18; mb = xcd*8 + local/18
// Inverse: g = ((mb&7)*18+nb)*8 + (mb>>3). On each XCD the 18 nb-panels of one
// mb run consecutively -> A panel fetched once per XCD, reused 18x from L2;
// per-XCD set = 8 A-panels (1.5MB) + B (3.5MB) ~ L2-resident.
// Rest identical to r9 (Wo-proven 128x128xBK32 2-phase, jj^((r>>1)&3) swizzle,
// gather rows via idx, tri-split epilogue with direct-transposed Vtc).
__global__ __launch_bounds__(256)
void gemm_qkv128(const f16* __restrict__ A, const f16* __restrict__ Bt,
                 const float* __restrict__ bias, f16* __restrict__ Qb,
                 f16* __restrict__ Kc, f16* __restrict__ Vt,
                 const int* __restrict__ idx, const int* __restrict__ cnt) {
  const int K = C_;
  __shared__ f16 lA[2 * 128 * 32];
  __shared__ f16 lB[2 * 128 * 32];
  const int tid = threadIdx.x;
  // XCD-aware remap (see header comment)
  const int g = blockIdx.y * 18 + blockIdx.x;  // linear dispatch id, x fastest
  const int xcd = g & 7, local = g >> 3;       // 144 blocks per xcd
  const int nb = local % 18;                   // 0..17
  const int mb = xcd * 8 + local / 18;         // 0..63
  const bool isQ = nb < 6;

  int b = 0, s0 = 0;
  if (!isQ) {
    b = mb >> 4;                       // 16 slot-tiles of 128 per batch
    s0 = (mb & 15) * 128;
    if (s0 >= cnt[b]) return;          // block-uniform exit before any barrier
  }

  const int lane = tid & 63, w = tid >> 6;
  const int wm = (w & 1) * 64, wn = (w >> 1) * 64;
  const int r15 = lane & 15, q4 = lane >> 4;
  const int rkey = (r15 >> 1) & 3;

  const int r0 = tid >> 2, jj = tid & 3;
  const int scol = (jj ^ ((r0 >> 1) & 3)) * 8;   // key same for r0+64 (64>>1 ≡ 0 mod 4)
  long ga0, ga1;
  if (isQ) { ga0 = (long)mb * 128 + r0; ga1 = ga0 + 64; }
  else {
    ga0 = (long)b * T_ + idx[b * T_ + s0 + r0];
    ga1 = (long)b * T_ + idx[b * T_ + s0 + r0 + 64];
  }
  const f16* pA0 = A + ga0 * K + scol;
  const f16* pA1 = A + ga1 * K + scol;
  const int ncol0 = isQ ? nb * 128 : C_ + (nb - 6) * 128;   // global qkv col base
  const f16* pB0 = Bt + (long)(ncol0 + r0) * K + scol;
  const f16* pB1 = pB0 + (long)64 * K;

  f32x4 acc[4][4];
#pragma unroll
  for (int i = 0; i < 4; i++)
#pragma unroll
    for (int j = 0; j < 4; j++) acc[i][j] = fzero4();

#define STAGE_QK(bufsel, kb) do {                                   \
  const int lb = (bufsel) * 4096;                                   \
  g2l16(pA0 + (kb), &lA[lb + tid * 8]);                             \
  g2l16(pA1 + (kb), &lA[lb + 2048 + tid * 8]);                      \
  g2l16(pB0 + (kb), &lB[lb + tid * 8]);                             \
  g2l16(pB1 + (kb), &lB[lb + 2048 + tid * 8]);                      \
} while (0)

#define COMPUTE_QK(bufsel) do {                                     \
  const int lb = (bufsel) * 4096;                                   \
  const int cofs = (q4 ^ rkey) * 8;                                 \
  f16x8 af[4], bfv[4];                                              \
  _Pragma("unroll")                                                 \
  for (int mi = 0; mi < 4; mi++)                                    \
    af[mi] = *(const f16x8*)&lA[lb + (wm + mi * 16 + r15) * 32 + cofs]; \
  _Pragma("unroll")                                                 \
  for (int ni = 0; ni < 4; ni++)                                    \
    bfv[ni] = *(const f16x8*)&lB[lb + (wn + ni * 16 + r15) * 32 + cofs]; \
  _Pragma("unroll")                                                 \
  for (int mi = 0; mi < 4; mi++)                                    \
    _Pragma("unroll")                                               \
    for (int ni = 0; ni < 4; ni++)                                  \
      acc[mi][ni] = __builtin_amdgcn_mfma_f32_16x16x32_f16(af[mi], bfv[ni], acc[mi][ni], 0, 0, 0); \
} while (0)

  STAGE_QK(0, 0);
  __syncthreads();

  int cur = 0;
  const int NT = K / 32;                 // 24
  for (int t = 0; t < NT - 1; t++) {
    STAGE_QK(cur ^ 1, (t + 1) * 32);
    COMPUTE_QK(cur);
    __syncthreads();
    cur ^= 1;
  }
  COMPUTE_QK(cur);

#undef STAGE_QK
#undef COMPUTE_QK

#pragma unroll
  for (int ni = 0; ni < 4; ni++) {
    const int gcol = ncol0 + wn + ni * 16 + r15;    // 0..2303
    const float bs = bias[gcol];
    if (isQ) {
#pragma unroll
      for (int mi = 0; mi < 4; mi++)
#pragma unroll
        for (int r = 0; r < 4; r++) {
          const long row = (long)mb * 128 + wm + mi * 16 + q4 * 4 + r;
          Qb[row * C_ + gcol] = (f16)(acc[mi][ni][r] + bs);
        }
    } else if (gcol < 2 * C_) {
      const int ocol = gcol - C_;
#pragma unroll
      for (int mi = 0; mi < 4; mi++)
#pragma unroll
        for (int r = 0; r < 4; r++) {
          const long row = (long)b * T_ + s0 + wm + mi * 16 + q4 * 4 + r;
          Kc[row * C_ + ocol] = (f16)(acc[mi][ni][r] + bs);
        }
    } else {
      // V transposed: Vtc[bh][d][slot]; 4 consecutive slots -> one f16x4 store
      const int vcol = gcol - 2 * C_;               // 0..767
      const int vh = vcol >> 6, d = vcol & 63;
      f16* dst = Vt + ((long)(b * H_ + vh) * D_ + d) * T_;
#pragma unroll
      for (int mi = 0; mi < 4; mi++) {
        const long slot = s0 + wm + mi * 16 + q4 * 4;
        f16x4 v4;
#pragma unroll
        for (int r = 0; r < 4; r++) v4[r] = (f16)(acc[mi][ni][r] + bs);
        *(f16x4*)&dst[slot] = v4;
      }
    }
  }
}

// ------- flash attention v2 (pinned 43-44.5us): g2l16-dbuf K/V staging, in-register
// P via cvt_pkrtz+permlane32_swap, setprio around MFMA, XCD swizzle. -------
__global__ __launch_bounds__(256, 4)
void attn_kernel(const f16* __restrict__ Qb, const f16* __restrict__ Kc,
                 const f16* __restrict__ vtc, const int* __restrict__ cnt,
                 f16* __restrict__ ctx) {
  __shared__ f16 Ks[2][64 * 64];
  __shared__ f16 Vs[2][64 * 64];
  __shared__ float Ls[4][32];
  const int tid = threadIdx.x, lane = tid & 63, w = tid >> 6;
  const int l31 = lane & 31, hh = lane >> 5;

  // bijective XCD swizzle: dispatch id g -> xcd g&7 handles 6 contiguous bh
  const int g = blockIdx.y * 16 + blockIdx.x;   // 0..767, dispatch order
  const int xcd = g & 7, local = g >> 3;        // 96 blocks per xcd
  const int bh = xcd * 6 + (local >> 4);        // 6 bh per xcd
  const int q0 = (local & 15) * 128;
  const int b = bh / H_, h = bh % H_;

  const f16* Qg = Qb + (long)(b * T_ + q0) * C_ + h * D_;
  const f16* Kbase = Kc + (long)b * T_ * C_ + h * D_;  // + slot*C_
  const f16* Vg = vtc + (long)bh * D_ * T_;            // [d][slot]
  const int nk = cnt[b];
  const int nkt = (nk + 63) >> 6;

  // Q frags direct from global, pre-scaled by 1/sqrt(D)*log2(e)
  const f16 qsc = (f16)0.18033688f;  // 0.125 * 1.44269504
  f16x8 bq[4];
#pragma unroll
  for (int j = 0; j < 4; j++) {
    f16x8 v = *(const f16x8*)(Qg + (long)(w * 32 + l31) * C_ + j * 16 + hh * 8);
#pragma unroll
    for (int e = 0; e < 8; e++) v[e] = v[e] * qsc;
    bq[j] = v;
  }

  // staging geometry: chunk c = w*128 + i*64 + lane (i=0,1); row r=c>>3, slot jj=c&7
  const int r_0 = w * 16 + (lane >> 3);        // i=0 row; i=1 row = r_0+8
  const int sc = ((lane & 7) ^ (r_0 & 7)) * 8; // source col, f16 units (same for i=0,1)
  const f16* Ksrc0 = Kbase + (long)r_0 * C_ + sc;
  const f16* Ksrc1 = Kbase + (long)(r_0 + 8) * C_ + sc;
  const f16* Vsrc0 = Vg + (long)r_0 * T_ + sc;
  const f16* Vsrc1 = Vg + (long)(r_0 + 8) * T_ + sc;
  const int ld0 = w * 1024 + lane * 8;         // f16 offset of chunk i=0
  const int ld1 = ld0 + 512;                   // i=1 (+64 chunks)

#define ATTN_STAGE(bs, kt) do {                                  \
    g2l16(Ksrc0 + (long)(kt) * C_, &Ks[bs][ld0]);                \
    g2l16(Ksrc1 + (long)(kt) * C_, &Ks[bs][ld1]);                \
    g2l16(Vsrc0 + (kt), &Vs[bs][ld0]);                           \
    g2l16(Vsrc1 + (kt), &Vs[bs][ld1]);                           \
  } while (0)

  float l_acc = 0.f;
  f32x16 O[2];
#pragma unroll
  for (int dt = 0; dt < 2; dt++)
#pragma unroll
    for (int r = 0; r < 16; r++) O[dt][r] = 0.f;

  const int swz = l31 & 7;  // read-side swizzle key (rows are 32-multiples + l31)

  ATTN_STAGE(0, 0);
  __syncthreads();

  int cur = 0;
  for (int t = 0; t < nkt; t++) {
    const int kt = t * 64;
    if (t + 1 < nkt) ATTN_STAGE(cur ^ 1, kt + 64);   // prefetch before compute

    u32x4 paw[4];
    const bool full = (kt + 64 <= nk);  // wave-uniform
#pragma unroll
    for (int t2 = 0; t2 < 2; t2++) {
      f32x16 acc;
      if (full) {
#pragma unroll
        for (int r = 0; r < 16; r++) acc[r] = 0.f;
      } else {
        const int kbase = kt + t2 * 32 + hh * 4;
#pragma unroll
        for (int g4 = 0; g4 < 4; g4++)
#pragma unroll
          for (int i = 0; i < 4; i++)
            acc[4 * g4 + i] = (kbase + 8 * g4 + i < nk) ? 0.f : -1e30f;
      }
      __builtin_amdgcn_s_setprio(1);
#pragma unroll
      for (int j = 0; j < 4; j++) {   // A=K[m=key=t2*32+l31][k=d chunk (j*2+hh)^swz]
        f16x8 ak = *(const f16x8*)&Ks[cur][(t2 * 32 + l31) * 64 + (((j * 2 + hh) ^ swz) << 3)];
        acc = __builtin_amdgcn_mfma_f32_32x32x16_f16(ak, bq[j], acc, 0, 0, 0);
      }
      __builtin_amdgcn_s_setprio(0);
      uint32_t wg[4], xg[4];
#pragma unroll
      for (int g4 = 0; g4 < 4; g4++) {
        const float p0 = __builtin_amdgcn_exp2f(acc[4 * g4 + 0]);
        const float p1 = __builtin_amdgcn_exp2f(acc[4 * g4 + 1]);
        const float p2 = __builtin_amdgcn_exp2f(acc[4 * g4 + 2]);
        const float p3 = __builtin_amdgcn_exp2f(acc[4 * g4 + 3]);
        l_acc += (p0 + p1) + (p2 + p3);
        wg[g4] = pk_u32(p0, p1);   // keys 8g+4hh+{0,1}
        xg[g4] = pk_u32(p2, p3);   // keys 8g+4hh+{2,3}
      }
#pragma unroll
      for (int jl = 0; jl < 2; jl++) {
        uint32_t w0 = wg[2 * jl], w2v = wg[2 * jl + 1];
        uint32_t w1 = xg[2 * jl], w3v = xg[2 * jl + 1];
        pl32swap(w0, w2v);
        pl32swap(w1, w3v);
        paw[2 * t2 + jl][0] = w0;  paw[2 * t2 + jl][1] = w1;
        paw[2 * t2 + jl][2] = w2v; paw[2 * t2 + jl][3] = w3v;
      }
    }

    // O += P V: A=P[q=l31][key], B=V[key][d=dt*32+l31] (Vs stores [d][key])
    __builtin_amdgcn_s_setprio(1);
#pragma unroll
    for (int j = 0; j < 4; j++) {
      const f16x8 pa = *(const f16x8*)&paw[j];
#pragma unroll
      for (int dt = 0; dt < 2; dt++) {
        const int vrow = dt * 32 + l31;
        f16x8 vb = *(const f16x8*)&Vs[cur][vrow * 64 + (((j * 2 + hh) ^ swz) << 3)];
        O[dt] = __builtin_amdgcn_mfma_f32_32x32x16_f16(pa, vb, O[dt], 0, 0, 0);
      }
    }
    __builtin_amdgcn_s_setprio(0);

    __syncthreads();   // drains prefetch (vmcnt 0) + all LDS reads before overwrite
    cur ^= 1;
  }
#undef ATTN_STAGE

  // l finalize: partner (xor 32) holds the complementary key subset for same q
  l_acc += __shfl_xor(l_acc, 32);
  asm volatile("s_waitcnt lgkmcnt(0)" ::: "memory");
  if (hh == 0) Ls[w][l31] = l_acc;
  asm volatile("s_waitcnt lgkmcnt(0)" ::: "memory");
#pragma unroll
  for (int g4 = 0; g4 < 4; g4++) {
    const f32x4 lv = *(const f32x4*)&Ls[w][g4 * 8 + hh * 4];  // broadcast
#pragma unroll
    for (int i = 0; i < 4; i++) {
      const float inv = 1.f / lv[i];
      const int row = b * T_ + q0 + w * 32 + g4 * 8 + hh * 4 + i;
#pragma unroll
      for (int dt = 0; dt < 2; dt++)
        ctx[(long)row * C_ + h * D_ + dt * 32 + l31] = (f16)(O[dt][4 * g4 + i] * inv);
    }
  }
}

extern "C" void kernel_launch(void* const* d_in, const int* in_sizes, int n_in,
                              void* d_out, int out_size, void* d_ws, size_t ws_size,
                              hipStream_t stream) {
  (void)in_sizes; (void)n_in; (void)out_size; (void)ws_size;
  const float* x    = (const float*)d_in[0];
  const int*   mask = (const int*)  d_in[1];
  const float* Wqkv = (const float*)d_in[2];
  const float* bqkv = (const float*)d_in[3];
  const float* Wo   = (const float*)d_in[4];
  const float* bo   = (const float*)d_in[5];
  float* out = (float*)d_out;

  char* ws = (char*)d_ws;
  const size_t OFF_WQKVT = 0;                         // 2304*768*2  = 3538944
  const size_t OFF_WOT   = OFF_WQKVT + 3538944;       // 768*768*2   = 1179648
  const size_t OFF_Q     = OFF_WOT + 1179648;         // 8192*768*2  = 12582912
  const size_t OFF_KC    = OFF_Q + 12582912;          // 4*2048*768*2= 12582912
  const size_t OFF_VT    = OFF_KC + 12582912;         // 48*64*2048*2= 12582912
  const size_t OFF_XH    = OFF_VT + 12582912;         // 8192*768*2  = 12582912 (xh, later ctx)
  const size_t OFF_IDX   = OFF_XH + 12582912;         // 4*2048*4    = 32768
  const size_t OFF_CNT   = OFF_IDX + 32768;           // 4*4
  f16* WqkvT = (f16*)(ws + OFF_WQKVT);
  f16* WoT   = (f16*)(ws + OFF_WOT);
  f16* Qb    = (f16*)(ws + OFF_Q);
  f16* Kc    = (f16*)(ws + OFF_KC);
  f16* Vtc   = (f16*)(ws + OFF_VT);
  f16* xh    = (f16*)(ws + OFF_XH);   // dead after QKV GEMM
  f16* ctx   = (f16*)(ws + OFF_XH);   // written by attn afterwards
  int* idx   = (int*)(ws + OFF_IDX);
  int* cnt   = (int*)(ws + OFF_CNT);

  prep_kernel<<<dim3(8480), 256, 0, stream>>>(Wqkv, WqkvT, Wo, WoT, x, xh, idx, cnt);
  compact_kernel<<<dim3(T_ / 256, B_), 256, 0, stream>>>(mask, idx, cnt);
  gemm_qkv128<<<dim3(18, 64), 256, 0, stream>>>(xh, WqkvT, bqkv, Qb, Kc, Vtc, idx, cnt);
  attn_kernel<<<dim3(16, 48), 256, 0, stream>>>(Qb, Kc, Vtc, cnt, ctx);
  gemm_bias_kernel<float><<<dim3(6, 64), 256, 0, stream>>>(ctx, WoT, bo, out, 768, 768);
}

// Round 11
// 187.032 us; speedup vs baseline: 1.0873x; 1.0873x over previous
//
#include <hip/hip_runtime.h>
#include <stdint.h>

#define AS1 __attribute__((address_space(1)))
#define AS3 __attribute__((address_space(3)))

typedef _Float16 f16;
typedef _Float16 f16x8 __attribute__((ext_vector_type(8)));
typedef _Float16 f16x4 __attribute__((ext_vector_type(4)));
typedef float    f32x4  __attribute__((ext_vector_type(4)));
typedef float    f32x16 __attribute__((ext_vector_type(16)));
typedef uint32_t u32x4  __attribute__((ext_vector_type(4)));
typedef uint32_t u32x2  __attribute__((ext_vector_type(2)));

#define B_  4
#define T_  2048
#define C_  768
#define H_  12
#define D_  64
#define M_  (B_*T_)      /* 8192 */
#define N1_ (3*C_)       /* 2304 */

__device__ __forceinline__ void g2l16(const void* g, void* l) {
  __builtin_amdgcn_global_load_lds((const AS1 void*)g, (AS3 void*)l, 16, 0, 0);
}

__device__ __forceinline__ f32x4 fzero4() { f32x4 z = {0.f, 0.f, 0.f, 0.f}; return z; }

__device__ __forceinline__ uint32_t pk_u32(float a, float b) {
  auto t = __builtin_amdgcn_cvt_pkrtz(a, b);  // 2 x f16 packed in 32 bits
  return *(uint32_t*)&t;
}

// permlane32_swap: new_d[l<32]=old_d[l], new_d[l>=32]=old_s[l-32];
//                  new_s[l<32]=old_d[l+32], new_s[l>=32]=old_s[l].
__device__ __forceinline__ void pl32swap(uint32_t& d, uint32_t& s) {
  u32x2 r = __builtin_amdgcn_permlane32_swap(d, s, false, false);
  d = r[0]; s = r[1];
}

// ------------- fused prep: Wqkv^T cvt | Wo^T cvt | x cvt | idx/cnt init -------------
__global__ __launch_bounds__(256)
void prep_kernel(const float* __restrict__ Wqkv, f16* __restrict__ WqkvT,
                 const float* __restrict__ Wo, f16* __restrict__ WoT,
                 const float* __restrict__ x, f16* __restrict__ xh,
                 int* __restrict__ idx, int* __restrict__ cnt) {
  __shared__ float tile[32][33];
  const int blk = blockIdx.x;
  if (blk < 2304) {
    const float* in; f16* out; int R, C, bx, by;
    if (blk < 1728) { in = Wqkv; out = WqkvT; R = 768; C = 2304; bx = blk % 72; by = blk / 72; }
    else { const int k = blk - 1728; in = Wo; out = WoT; R = 768; C = 768; bx = k % 24; by = k / 24; }
    const int tx = threadIdx.x & 31, ty = threadIdx.x >> 5;
    const int c0 = bx * 32, r0 = by * 32;
#pragma unroll
    for (int i = 0; i < 32; i += 8)
      tile[ty + i][tx] = in[(long)(r0 + ty + i) * C + c0 + tx];
    __syncthreads();
#pragma unroll
    for (int i = 0; i < 32; i += 8)
      out[(long)(c0 + ty + i) * R + r0 + tx] = (f16)tile[tx][ty + i];
  } else if (blk < 8448) {
    const int i = ((blk - 2304) * 256 + threadIdx.x) * 4;
    const float4 v = *(const float4*)(x + i);
    f16x4 o = {(f16)v.x, (f16)v.y, (f16)v.z, (f16)v.w};
    *(f16x4*)(xh + i) = o;
  } else {
    const int g = (blk - 8448) * 256 + threadIdx.x;
    idx[g] = 0;           // pad entries point at row 0 (valid; killed by key>=nk C-init)
    if (g < B_) cnt[g] = 0;
  }
}

// ------------- mask compaction: idx[b][slot]=t for kept keys (mask==0) -------------
__global__ __launch_bounds__(256)
void compact_kernel(const int* __restrict__ mask, int* __restrict__ idx,
                    int* __restrict__ cnt) {
  const int b = blockIdx.y;
  const int t = blockIdx.x * 256 + threadIdx.x;
  if (mask[b * T_ + t] == 0) {                 // keep where mask==0 (module quirk)
    const int s = atomicAdd(&cnt[b], 1);       // device-scope
    idx[b * T_ + s] = t;
  }
}

// ------- Wo GEMM (r7-proven): 128x128xBK32, 2-phase dbuf, jj^((r>>1)&3) swizzle -------
template <typename OutT>
__global__ __launch_bounds__(256)
void gemm_bias_kernel(const f16* __restrict__ A, const f16* __restrict__ Bt,
                      const float* __restrict__ bias, OutT* __restrict__ Cc,
                      int K, int ldc) {
  __shared__ f16 lA[2 * 128 * 32];
  __shared__ f16 lB[2 * 128 * 32];
  const int tid = threadIdx.x;
  const int n0 = blockIdx.x * 128, m0 = blockIdx.y * 128;
  const int lane = tid & 63, w = tid >> 6;
  const int wm = (w & 1) * 64, wn = (w >> 1) * 64;
  const int r15 = lane & 15, q4 = lane >> 4;
  const int rkey = (r15 >> 1) & 3;             // read-side swizzle key

  const int r0 = tid >> 2, jj = tid & 3;
  const int scol = (jj ^ ((r0 >> 1) & 3)) * 8; // f16 units, same for i=0,1
  const f16* pA0 = A + (long)(m0 + r0) * K + scol;
  const f16* pB0 = Bt + (long)(n0 + r0) * K + scol;
  const long rstep = (long)64 * K;             // i=1 rows are +64

  f32x4 acc[4][4];
#pragma unroll
  for (int i = 0; i < 4; i++)
#pragma unroll
    for (int j = 0; j < 4; j++) acc[i][j] = fzero4();

#define STAGE_WO(bufsel, kb) do {                                   \
  const int lb = (bufsel) * 4096;                                   \
  g2l16(pA0 + (kb), &lA[lb + tid * 8]);                             \
  g2l16(pA0 + rstep + (kb), &lA[lb + 2048 + tid * 8]);              \
  g2l16(pB0 + (kb), &lB[lb + tid * 8]);                             \
  g2l16(pB0 + rstep + (kb), &lB[lb + 2048 + tid * 8]);              \
} while (0)

#define COMPUTE_WO(bufsel) do {                                     \
  const int lb = (bufsel) * 4096;                                   \
  const int cofs = (q4 ^ rkey) * 8;                                 \
  f16x8 af[4], bfv[4];                                              \
  _Pragma("unroll")                                                 \
  for (int mi = 0; mi < 4; mi++)                                    \
    af[mi] = *(const f16x8*)&lA[lb + (wm + mi * 16 + r15) * 32 + cofs]; \
  _Pragma("unroll")                                                 \
  for (int ni = 0; ni < 4; ni++)                                    \
    bfv[ni] = *(const f16x8*)&lB[lb + (wn + ni * 16 + r15) * 32 + cofs]; \
  _Pragma("unroll")                                                 \
  for (int mi = 0; mi < 4; mi++)                                    \
    _Pragma("unroll")                                               \
    for (int ni = 0; ni < 4; ni++)                                  \
      acc[mi][ni] = __builtin_amdgcn_mfma_f32_16x16x32_f16(af[mi], bfv[ni], acc[mi][ni], 0, 0, 0); \
} while (0)

  STAGE_WO(0, 0);
  __syncthreads();

  int cur = 0;
  const int NT = K / 32;                 // 24
  for (int t = 0; t < NT - 1; t++) {
    STAGE_WO(cur ^ 1, (t + 1) * 32);     // issue next-tile loads FIRST
    COMPUTE_WO(cur);                     // ds_read + MFMA hide the load flight
    __syncthreads();                     // one drain+barrier per K-tile
    cur ^= 1;
  }
  COMPUTE_WO(cur);

#undef STAGE_WO
#undef COMPUTE_WO

#pragma unroll
  for (int ni = 0; ni < 4; ni++) {
    const int col = n0 + wn + ni * 16 + r15;
    const float bs = bias[col];
#pragma unroll
    for (int mi = 0; mi < 4; mi++) {
#pragma unroll
      for (int r = 0; r < 4; r++) {
        const int row = m0 + wm + mi * 16 + q4 * 4 + r;
        Cc[(long)row * ldc + col] = (OutT)(acc[mi][ni][r] + bs);
      }
    }
  }
}

// ------- fused masked QKV GEMM v5: r9 structure + BALANCED XCD remap.
// r10 post-mortem: remap mb=xcd*8+local/18 halved FETCH (51->24.6MB, confirmed)
// but gave each XCD a CONTIGUOUS mb run -> KV early-exit (s0=(mb&15)*128>=cnt)
// correlated per XCD: half the XCDs lost all KV work, the rest carried 2x ->
// 44.8->59.2us. Fix: mb = (local/18)*8 + xcd (bijective over (k,xcd)). Each XCD
// now gets mb ∈ {xcd, 8+xcd, ..., 56+xcd}: exactly 4 of 8 mb groups have
// mb&15<8 (working KV), 4 exit -> identical KV load per XCD, while the 18
// nb-blocks of one mb stay consecutive on one XCD (A-panel fetched once/XCD,
// 18x L2 reuse -> keeps the FETCH halving).
// Rest identical to r9/r10 (Wo-proven 128x128xBK32 2-phase, jj^((r>>1)&3)
// swizzle, gather rows via idx, tri-split epilogue with direct-transposed Vtc).
__global__ __launch_bounds__(256)
void gemm_qkv128(const f16* __restrict__ A, const f16* __restrict__ Bt,
                 const float* __restrict__ bias, f16* __restrict__ Qb,
                 f16* __restrict__ Kc, f16* __restrict__ Vt,
                 const int* __restrict__ idx, const int* __restrict__ cnt) {
  const int K = C_;
  __shared__ f16 lA[2 * 128 * 32];
  __shared__ f16 lB[2 * 128 * 32];
  const int tid = threadIdx.x;
  // balanced XCD-aware remap (see header comment)
  const int g = blockIdx.y * 18 + blockIdx.x;  // linear dispatch id, x fastest
  const int xcd = g & 7, local = g >> 3;       // 144 blocks per xcd
  const int nb = local % 18;                   // 0..17
  const int mb = (local / 18) * 8 + xcd;       // 0..63, balanced striping
  const bool isQ = nb < 6;

  int b = 0, s0 = 0;
  if (!isQ) {
    b = mb >> 4;                       // 16 slot-tiles of 128 per batch
    s0 = (mb & 15) * 128;
    if (s0 >= cnt[b]) return;          // block-uniform exit before any barrier
  }

  const int lane = tid & 63, w = tid >> 6;
  const int wm = (w & 1) * 64, wn = (w >> 1) * 64;
  const int r15 = lane & 15, q4 = lane >> 4;
  const int rkey = (r15 >> 1) & 3;

  const int r0 = tid >> 2, jj = tid & 3;
  const int scol = (jj ^ ((r0 >> 1) & 3)) * 8;   // key same for r0+64 (64>>1 ≡ 0 mod 4)
  long ga0, ga1;
  if (isQ) { ga0 = (long)mb * 128 + r0; ga1 = ga0 + 64; }
  else {
    ga0 = (long)b * T_ + idx[b * T_ + s0 + r0];
    ga1 = (long)b * T_ + idx[b * T_ + s0 + r0 + 64];
  }
  const f16* pA0 = A + ga0 * K + scol;
  const f16* pA1 = A + ga1 * K + scol;
  const int ncol0 = isQ ? nb * 128 : C_ + (nb - 6) * 128;   // global qkv col base
  const f16* pB0 = Bt + (long)(ncol0 + r0) * K + scol;
  const f16* pB1 = pB0 + (long)64 * K;

  f32x4 acc[4][4];
#pragma unroll
  for (int i = 0; i < 4; i++)
#pragma unroll
    for (int j = 0; j < 4; j++) acc[i][j] = fzero4();

#define STAGE_QK(bufsel, kb) do {                                   \
  const int lb = (bufsel) * 4096;                                   \
  g2l16(pA0 + (kb), &lA[lb + tid * 8]);                             \
  g2l16(pA1 + (kb), &lA[lb + 2048 + tid * 8]);                      \
  g2l16(pB0 + (kb), &lB[lb + tid * 8]);                             \
  g2l16(pB1 + (kb), &lB[lb + 2048 + tid * 8]);                      \
} while (0)

#define COMPUTE_QK(bufsel) do {                                     \
  const int lb = (bufsel) * 4096;                                   \
  const int cofs = (q4 ^ rkey) * 8;                                 \
  f16x8 af[4], bfv[4];                                              \
  _Pragma("unroll")                                                 \
  for (int mi = 0; mi < 4; mi++)                                    \
    af[mi] = *(const f16x8*)&lA[lb + (wm + mi * 16 + r15) * 32 + cofs]; \
  _Pragma("unroll")                                                 \
  for (int ni = 0; ni < 4; ni++)                                    \
    bfv[ni] = *(const f16x8*)&lB[lb + (wn + ni * 16 + r15) * 32 + cofs]; \
  _Pragma("unroll")                                                 \
  for (int mi = 0; mi < 4; mi++)                                    \
    _Pragma("unroll")                                               \
    for (int ni = 0; ni < 4; ni++)                                  \
      acc[mi][ni] = __builtin_amdgcn_mfma_f32_16x16x32_f16(af[mi], bfv[ni], acc[mi][ni], 0, 0, 0); \
} while (0)

  STAGE_QK(0, 0);
  __syncthreads();

  int cur = 0;
  const int NT = K / 32;                 // 24
  for (int t = 0; t < NT - 1; t++) {
    STAGE_QK(cur ^ 1, (t + 1) * 32);
    COMPUTE_QK(cur);
    __syncthreads();
    cur ^= 1;
  }
  COMPUTE_QK(cur);

#undef STAGE_QK
#undef COMPUTE_QK

#pragma unroll
  for (int ni = 0; ni < 4; ni++) {
    const int gcol = ncol0 + wn + ni * 16 + r15;    // 0..2303
    const float bs = bias[gcol];
    if (isQ) {
#pragma unroll
      for (int mi = 0; mi < 4; mi++)
#pragma unroll
        for (int r = 0; r < 4; r++) {
          const long row = (long)mb * 128 + wm + mi * 16 + q4 * 4 + r;
          Qb[row * C_ + gcol] = (f16)(acc[mi][ni][r] + bs);
        }
    } else if (gcol < 2 * C_) {
      const int ocol = gcol - C_;
#pragma unroll
      for (int mi = 0; mi < 4; mi++)
#pragma unroll
        for (int r = 0; r < 4; r++) {
          const long row = (long)b * T_ + s0 + wm + mi * 16 + q4 * 4 + r;
          Kc[row * C_ + ocol] = (f16)(acc[mi][ni][r] + bs);
        }
    } else {
      // V transposed: Vtc[bh][d][slot]; 4 consecutive slots -> one f16x4 store
      const int vcol = gcol - 2 * C_;               // 0..767
      const int vh = vcol >> 6, d = vcol & 63;
      f16* dst = Vt + ((long)(b * H_ + vh) * D_ + d) * T_;
#pragma unroll
      for (int mi = 0; mi < 4; mi++) {
        const long slot = s0 + wm + mi * 16 + q4 * 4;
        f16x4 v4;
#pragma unroll
        for (int r = 0; r < 4; r++) v4[r] = (f16)(acc[mi][ni][r] + bs);
        *(f16x4*)&dst[slot] = v4;
      }
    }
  }
}

// ------- flash attention v2 (pinned 43-44.5us): g2l16-dbuf K/V staging, in-register
// P via cvt_pkrtz+permlane32_swap, setprio around MFMA, XCD swizzle. -------
__global__ __launch_bounds__(256, 4)
void attn_kernel(const f16* __restrict__ Qb, const f16* __restrict__ Kc,
                 const f16* __restrict__ vtc, const int* __restrict__ cnt,
                 f16* __restrict__ ctx) {
  __shared__ f16 Ks[2][64 * 64];
  __shared__ f16 Vs[2][64 * 64];
  __shared__ float Ls[4][32];
  const int tid = threadIdx.x, lane = tid & 63, w = tid >> 6;
  const int l31 = lane & 31, hh = lane >> 5;

  // bijective XCD swizzle: dispatch id g -> xcd g&7 handles 6 contiguous bh
  const int g = blockIdx.y * 16 + blockIdx.x;   // 0..767, dispatch order
  const int xcd = g & 7, local = g >> 3;        // 96 blocks per xcd
  const int bh = xcd * 6 + (local >> 4);        // 6 bh per xcd
  const int q0 = (local & 15) * 128;
  const int b = bh / H_, h = bh % H_;

  const f16* Qg = Qb + (long)(b * T_ + q0) * C_ + h * D_;
  const f16* Kbase = Kc + (long)b * T_ * C_ + h * D_;  // + slot*C_
  const f16* Vg = vtc + (long)bh * D_ * T_;            // [d][slot]
  const int nk = cnt[b];
  const int nkt = (nk + 63) >> 6;

  // Q frags direct from global, pre-scaled by 1/sqrt(D)*log2(e)
  const f16 qsc = (f16)0.18033688f;  // 0.125 * 1.44269504
  f16x8 bq[4];
#pragma unroll
  for (int j = 0; j < 4; j++) {
    f16x8 v = *(const f16x8*)(Qg + (long)(w * 32 + l31) * C_ + j * 16 + hh * 8);
#pragma unroll
    for (int e = 0; e < 8; e++) v[e] = v[e] * qsc;
    bq[j] = v;
  }

  // staging geometry: chunk c = w*128 + i*64 + lane (i=0,1); row r=c>>3, slot jj=c&7
  const int r_0 = w * 16 + (lane >> 3);        // i=0 row; i=1 row = r_0+8
  const int sc = ((lane & 7) ^ (r_0 & 7)) * 8; // source col, f16 units (same for i=0,1)
  const f16* Ksrc0 = Kbase + (long)r_0 * C_ + sc;
  const f16* Ksrc1 = Kbase + (long)(r_0 + 8) * C_ + sc;
  const f16* Vsrc0 = Vg + (long)r_0 * T_ + sc;
  const f16* Vsrc1 = Vg + (long)(r_0 + 8) * T_ + sc;
  const int ld0 = w * 1024 + lane * 8;         // f16 offset of chunk i=0
  const int ld1 = ld0 + 512;                   // i=1 (+64 chunks)

#define ATTN_STAGE(bs, kt) do {                                  \
    g2l16(Ksrc0 + (long)(kt) * C_, &Ks[bs][ld0]);                \
    g2l16(Ksrc1 + (long)(kt) * C_, &Ks[bs][ld1]);                \
    g2l16(Vsrc0 + (kt), &Vs[bs][ld0]);                           \
    g2l16(Vsrc1 + (kt), &Vs[bs][ld1]);                           \
  } while (0)

  float l_acc = 0.f;
  f32x16 O[2];
#pragma unroll
  for (int dt = 0; dt < 2; dt++)
#pragma unroll
    for (int r = 0; r < 16; r++) O[dt][r] = 0.f;

  const int swz = l31 & 7;  // read-side swizzle key (rows are 32-multiples + l31)

  ATTN_STAGE(0, 0);
  __syncthreads();

  int cur = 0;
  for (int t = 0; t < nkt; t++) {
    const int kt = t * 64;
    if (t + 1 < nkt) ATTN_STAGE(cur ^ 1, kt + 64);   // prefetch before compute

    u32x4 paw[4];
    const bool full = (kt + 64 <= nk);  // wave-uniform
#pragma unroll
    for (int t2 = 0; t2 < 2; t2++) {
      f32x16 acc;
      if (full) {
#pragma unroll
        for (int r = 0; r < 16; r++) acc[r] = 0.f;
      } else {
        const int kbase = kt + t2 * 32 + hh * 4;
#pragma unroll
        for (int g4 = 0; g4 < 4; g4++)
#pragma unroll
          for (int i = 0; i < 4; i++)
            acc[4 * g4 + i] = (kbase + 8 * g4 + i < nk) ? 0.f : -1e30f;
      }
      __builtin_amdgcn_s_setprio(1);
#pragma unroll
      for (int j = 0; j < 4; j++) {   // A=K[m=key=t2*32+l31][k=d chunk (j*2+hh)^swz]
        f16x8 ak = *(const f16x8*)&Ks[cur][(t2 * 32 + l31) * 64 + (((j * 2 + hh) ^ swz) << 3)];
        acc = __builtin_amdgcn_mfma_f32_32x32x16_f16(ak, bq[j], acc, 0, 0, 0);
      }
      __builtin_amdgcn_s_setprio(0);
      uint32_t wg[4], xg[4];
#pragma unroll
      for (int g4 = 0; g4 < 4; g4++) {
        const float p0 = __builtin_amdgcn_exp2f(acc[4 * g4 + 0]);
        const float p1 = __builtin_amdgcn_exp2f(acc[4 * g4 + 1]);
        const float p2 = __builtin_amdgcn_exp2f(acc[4 * g4 + 2]);
        const float p3 = __builtin_amdgcn_exp2f(acc[4 * g4 + 3]);
        l_acc += (p0 + p1) + (p2 + p3);
        wg[g4] = pk_u32(p0, p1);   // keys 8g+4hh+{0,1}
        xg[g4] = pk_u32(p2, p3);   // keys 8g+4hh+{2,3}
      }
#pragma unroll
      for (int jl = 0; jl < 2; jl++) {
        uint32_t w0 = wg[2 * jl], w2v = wg[2 * jl + 1];
        uint32_t w1 = xg[2 * jl], w3v = xg[2 * jl + 1];
        pl32swap(w0, w2v);
        pl32swap(w1, w3v);
        paw[2 * t2 + jl][0] = w0;  paw[2 * t2 + jl][1] = w1;
        paw[2 * t2 + jl][2] = w2v; paw[2 * t2 + jl][3] = w3v;
      }
    }

    // O += P V: A=P[q=l31][key], B=V[key][d=dt*32+l31] (Vs stores [d][key])
    __builtin_amdgcn_s_setprio(1);
#pragma unroll
    for (int j = 0; j < 4; j++) {
      const f16x8 pa = *(const f16x8*)&paw[j];
#pragma unroll
      for (int dt = 0; dt < 2; dt++) {
        const int vrow = dt * 32 + l31;
        f16x8 vb = *(const f16x8*)&Vs[cur][vrow * 64 + (((j * 2 + hh) ^ swz) << 3)];
        O[dt] = __builtin_amdgcn_mfma_f32_32x32x16_f16(pa, vb, O[dt], 0, 0, 0);
      }
    }
    __builtin_amdgcn_s_setprio(0);

    __syncthreads();   // drains prefetch (vmcnt 0) + all LDS reads before overwrite
    cur ^= 1;
  }
#undef ATTN_STAGE

  // l finalize: partner (xor 32) holds the complementary key subset for same q
  l_acc += __shfl_xor(l_acc, 32);
  asm volatile("s_waitcnt lgkmcnt(0)" ::: "memory");
  if (hh == 0) Ls[w][l31] = l_acc;
  asm volatile("s_waitcnt lgkmcnt(0)" ::: "memory");
#pragma unroll
  for (int g4 = 0; g4 < 4; g4++) {
    const f32x4 lv = *(const f32x4*)&Ls[w][g4 * 8 + hh * 4];  // broadcast
#pragma unroll
    for (int i = 0; i < 4; i++) {
      const float inv = 1.f / lv[i];
      const int row = b * T_ + q0 + w * 32 + g4 * 8 + hh * 4 + i;
#pragma unroll
      for (int dt = 0; dt < 2; dt++)
        ctx[(long)row * C_ + h * D_ + dt * 32 + l31] = (f16)(O[dt][4 * g4 + i] * inv);
    }
  }
}

extern "C" void kernel_launch(void* const* d_in, const int* in_sizes, int n_in,
                              void* d_out, int out_size, void* d_ws, size_t ws_size,
                              hipStream_t stream) {
  (void)in_sizes; (void)n_in; (void)out_size; (void)ws_size;
  const float* x    = (const float*)d_in[0];
  const int*   mask = (const int*)  d_in[1];
  const float* Wqkv = (const float*)d_in[2];
  const float* bqkv = (const float*)d_in[3];
  const float* Wo   = (const float*)d_in[4];
  const float* bo   = (const float*)d_in[5];
  float* out = (float*)d_out;

  char* ws = (char*)d_ws;
  const size_t OFF_WQKVT = 0;                         // 2304*768*2  = 3538944
  const size_t OFF_WOT   = OFF_WQKVT + 3538944;       // 768*768*2   = 1179648
  const size_t OFF_Q     = OFF_WOT + 1179648;         // 8192*768*2  = 12582912
  const size_t OFF_KC    = OFF_Q + 12582912;          // 4*2048*768*2= 12582912
  const size_t OFF_VT    = OFF_KC + 12582912;         // 48*64*2048*2= 12582912
  const size_t OFF_XH    = OFF_VT + 12582912;         // 8192*768*2  = 12582912 (xh, later ctx)
  const size_t OFF_IDX   = OFF_XH + 12582912;         // 4*2048*4    = 32768
  const size_t OFF_CNT   = OFF_IDX + 32768;           // 4*4
  f16* WqkvT = (f16*)(ws + OFF_WQKVT);
  f16* WoT   = (f16*)(ws + OFF_WOT);
  f16* Qb    = (f16*)(ws + OFF_Q);
  f16* Kc    = (f16*)(ws + OFF_KC);
  f16* Vtc   = (f16*)(ws + OFF_VT);
  f16* xh    = (f16*)(ws + OFF_XH);   // dead after QKV GEMM
  f16* ctx   = (f16*)(ws + OFF_XH);   // written by attn afterwards
  int* idx   = (int*)(ws + OFF_IDX);
  int* cnt   = (int*)(ws + OFF_CNT);

  prep_kernel<<<dim3(8480), 256, 0, stream>>>(Wqkv, WqkvT, Wo, WoT, x, xh, idx, cnt);
  compact_kernel<<<dim3(T_ / 256, B_), 256, 0, stream>>>(mask, idx, cnt);
  gemm_qkv128<<<dim3(18, 64), 256, 0, stream>>>(xh, WqkvT, bqkv, Qb, Kc, Vtc, idx, cnt);
  attn_kernel<<<dim3(16, 48), 256, 0, stream>>>(Qb, Kc, Vtc, cnt, ctx);
  gemm_bias_kernel<float><<<dim3(6, 64), 256, 0, stream>>>(ctx, WoT, bo, out, 768, 768);
}

// Round 12
// 185.497 us; speedup vs baseline: 1.0963x; 1.0083x over previous
//
#include <hip/hip_runtime.h>
#include <stdint.h>

#define AS1 __attribute__((address_space(1)))
#define AS3 __attribute__((address_space(3)))

typedef _Float16 f16;
typedef _Float16 f16x8 __attribute__((ext_vector_type(8)));
typedef _Float16 f16x4 __attribute__((ext_vector_type(4)));
typedef float    f32x4  __attribute__((ext_vector_type(4)));
typedef float    f32x16 __attribute__((ext_vector_type(16)));
typedef uint32_t u32x4  __attribute__((ext_vector_type(4)));
typedef uint32_t u32x2  __attribute__((ext_vector_type(2)));

#define B_  4
#define T_  2048
#define C_  768
#define H_  12
#define D_  64
#define M_  (B_*T_)      /* 8192 */
#define N1_ (3*C_)       /* 2304 */

__device__ __forceinline__ void g2l16(const void* g, void* l) {
  __builtin_amdgcn_global_load_lds((const AS1 void*)g, (AS3 void*)l, 16, 0, 0);
}

__device__ __forceinline__ f32x4 fzero4() { f32x4 z = {0.f, 0.f, 0.f, 0.f}; return z; }

__device__ __forceinline__ uint32_t pk_u32(float a, float b) {
  auto t = __builtin_amdgcn_cvt_pkrtz(a, b);  // 2 x f16 packed in 32 bits
  return *(uint32_t*)&t;
}

// permlane32_swap: new_d[l<32]=old_d[l], new_d[l>=32]=old_s[l-32];
//                  new_s[l<32]=old_d[l+32], new_s[l>=32]=old_s[l].
__device__ __forceinline__ void pl32swap(uint32_t& d, uint32_t& s) {
  u32x2 r = __builtin_amdgcn_permlane32_swap(d, s, false, false);
  d = r[0]; s = r[1];
}

// ------------- fused prep: Wqkv^T | Wo^T | x cvt | PER-BATCH MASK COMPACTION -------
// blocks [0,1728): Wqkv transpose; [1728,2304): Wo transpose; [2304,8448): x cvt;
// [8448,8452): per-b compaction via block-local prefix scan (NO atomics, NO init
// dependency -> the former compact_kernel launch is eliminated; 5 -> 4 launches).
// Compaction block b: 256 threads x 8 masks each; Hillis-Steele scan in LDS;
// kept slots written in ASCENDING t order (bonus: QKV's KV row-gather becomes
// near-sequential); pads [cnt,2048) -> 0 (row 0 finite, killed by attn's -1e30
// C-init); cnt[b] = total. Kept/pad ranges disjoint -> no extra sync needed.
__global__ __launch_bounds__(256)
void prep_kernel(const float* __restrict__ Wqkv, f16* __restrict__ WqkvT,
                 const float* __restrict__ Wo, f16* __restrict__ WoT,
                 const float* __restrict__ x, f16* __restrict__ xh,
                 const int* __restrict__ mask,
                 int* __restrict__ idx, int* __restrict__ cnt) {
  __shared__ float tile[32][33];
  __shared__ int ps[256];
  const int blk = blockIdx.x;
  const int tid = threadIdx.x;
  if (blk < 2304) {
    const float* in; f16* out; int R, C, bx, by;
    if (blk < 1728) { in = Wqkv; out = WqkvT; R = 768; C = 2304; bx = blk % 72; by = blk / 72; }
    else { const int k = blk - 1728; in = Wo; out = WoT; R = 768; C = 768; bx = k % 24; by = k / 24; }
    const int tx = tid & 31, ty = tid >> 5;
    const int c0 = bx * 32, r0 = by * 32;
#pragma unroll
    for (int i = 0; i < 32; i += 8)
      tile[ty + i][tx] = in[(long)(r0 + ty + i) * C + c0 + tx];
    __syncthreads();
#pragma unroll
    for (int i = 0; i < 32; i += 8)
      out[(long)(c0 + ty + i) * R + r0 + tx] = (f16)tile[tx][ty + i];
  } else if (blk < 8448) {
    const int i = ((blk - 2304) * 256 + tid) * 4;
    const float4 v = *(const float4*)(x + i);
    f16x4 o = {(f16)v.x, (f16)v.y, (f16)v.z, (f16)v.w};
    *(f16x4*)(xh + i) = o;
  } else {
    const int b = blk - 8448;
    const int base = b * T_;
    int keep[8], c = 0;
#pragma unroll
    for (int i = 0; i < 8; i++) {
      keep[i] = (mask[base + tid * 8 + i] == 0) ? 1 : 0;  // keep where mask==0
      c += keep[i];
    }
    ps[tid] = c;
    __syncthreads();
    // Hillis-Steele inclusive scan over 256 counts
    for (int off = 1; off < 256; off <<= 1) {
      const int v = ps[tid];
      const int add = (tid >= off) ? ps[tid - off] : 0;
      __syncthreads();
      ps[tid] = v + add;
      __syncthreads();
    }
    const int total = ps[255];
    int o = ps[tid] - c;               // exclusive prefix
#pragma unroll
    for (int i = 0; i < 8; i++)
      if (keep[i]) idx[base + (o++)] = tid * 8 + i;
    for (int s = total + tid; s < T_; s += 256) idx[base + s] = 0;  // pads (disjoint range)
    if (tid == 0) cnt[b] = total;
  }
}

// ------- Wo GEMM (r7-proven): 128x128xBK32, 2-phase dbuf, jj^((r>>1)&3) swizzle -------
template <typename OutT>
__global__ __launch_bounds__(256)
void gemm_bias_kernel(const f16* __restrict__ A, const f16* __restrict__ Bt,
                      const float* __restrict__ bias, OutT* __restrict__ Cc,
                      int K, int ldc) {
  __shared__ f16 lA[2 * 128 * 32];
  __shared__ f16 lB[2 * 128 * 32];
  const int tid = threadIdx.x;
  const int n0 = blockIdx.x * 128, m0 = blockIdx.y * 128;
  const int lane = tid & 63, w = tid >> 6;
  const int wm = (w & 1) * 64, wn = (w >> 1) * 64;
  const int r15 = lane & 15, q4 = lane >> 4;
  const int rkey = (r15 >> 1) & 3;             // read-side swizzle key

  const int r0 = tid >> 2, jj = tid & 3;
  const int scol = (jj ^ ((r0 >> 1) & 3)) * 8; // f16 units, same for i=0,1
  const f16* pA0 = A + (long)(m0 + r0) * K + scol;
  const f16* pB0 = Bt + (long)(n0 + r0) * K + scol;
  const long rstep = (long)64 * K;             // i=1 rows are +64

  f32x4 acc[4][4];
#pragma unroll
  for (int i = 0; i < 4; i++)
#pragma unroll
    for (int j = 0; j < 4; j++) acc[i][j] = fzero4();

#define STAGE_WO(bufsel, kb) do {                                   \
  const int lb = (bufsel) * 4096;                                   \
  g2l16(pA0 + (kb), &lA[lb + tid * 8]);                             \
  g2l16(pA0 + rstep + (kb), &lA[lb + 2048 + tid * 8]);              \
  g2l16(pB0 + (kb), &lB[lb + tid * 8]);                             \
  g2l16(pB0 + rstep + (kb), &lB[lb + 2048 + tid * 8]);              \
} while (0)

#define COMPUTE_WO(bufsel) do {                                     \
  const int lb = (bufsel) * 4096;                                   \
  const int cofs = (q4 ^ rkey) * 8;                                 \
  f16x8 af[4], bfv[4];                                              \
  _Pragma("unroll")                                                 \
  for (int mi = 0; mi < 4; mi++)                                    \
    af[mi] = *(const f16x8*)&lA[lb + (wm + mi * 16 + r15) * 32 + cofs]; \
  _Pragma("unroll")                                                 \
  for (int ni = 0; ni < 4; ni++)                                    \
    bfv[ni] = *(const f16x8*)&lB[lb + (wn + ni * 16 + r15) * 32 + cofs]; \
  _Pragma("unroll")                                                 \
  for (int mi = 0; mi < 4; mi++)                                    \
    _Pragma("unroll")                                               \
    for (int ni = 0; ni < 4; ni++)                                  \
      acc[mi][ni] = __builtin_amdgcn_mfma_f32_16x16x32_f16(af[mi], bfv[ni], acc[mi][ni], 0, 0, 0); \
} while (0)

  STAGE_WO(0, 0);
  __syncthreads();

  int cur = 0;
  const int NT = K / 32;                 // 24
  for (int t = 0; t < NT - 1; t++) {
    STAGE_WO(cur ^ 1, (t + 1) * 32);     // issue next-tile loads FIRST
    COMPUTE_WO(cur);                     // ds_read + MFMA hide the load flight
    __syncthreads();                     // one drain+barrier per K-tile
    cur ^= 1;
  }
  COMPUTE_WO(cur);

#undef STAGE_WO
#undef COMPUTE_WO

#pragma unroll
  for (int ni = 0; ni < 4; ni++) {
    const int col = n0 + wn + ni * 16 + r15;
    const float bs = bias[col];
#pragma unroll
    for (int mi = 0; mi < 4; mi++) {
#pragma unroll
      for (int r = 0; r < 4; r++) {
        const int row = m0 + wm + mi * 16 + q4 * 4 + r;
        Cc[(long)row * ldc + col] = (OutT)(acc[mi][ni][r] + bs);
      }
    }
  }
}

// ------- fused masked QKV GEMM v5 (r11-proven): balanced XCD remap, Wo-structure
// 128x128xBK32 2-phase, jj^((r>>1)&3) swizzle, gather rows via idx, tri-split
// epilogue with direct-transposed Vtc. -------
__global__ __launch_bounds__(256)
void gemm_qkv128(const f16* __restrict__ A, const f16* __restrict__ Bt,
                 const float* __restrict__ bias, f16* __restrict__ Qb,
                 f16* __restrict__ Kc, f16* __restrict__ Vt,
                 const int* __restrict__ idx, const int* __restrict__ cnt) {
  const int K = C_;
  __shared__ f16 lA[2 * 128 * 32];
  __shared__ f16 lB[2 * 128 * 32];
  const int tid = threadIdx.x;
  // balanced XCD-aware remap (r11): panels grouped per XCD, KV work striped evenly
  const int g = blockIdx.y * 18 + blockIdx.x;  // linear dispatch id, x fastest
  const int xcd = g & 7, local = g >> 3;       // 144 blocks per xcd
  const int nb = local % 18;                   // 0..17
  const int mb = (local / 18) * 8 + xcd;       // 0..63, balanced striping
  const bool isQ = nb < 6;

  int b = 0, s0 = 0;
  if (!isQ) {
    b = mb >> 4;                       // 16 slot-tiles of 128 per batch
    s0 = (mb & 15) * 128;
    if (s0 >= cnt[b]) return;          // block-uniform exit before any barrier
  }

  const int lane = tid & 63, w = tid >> 6;
  const int wm = (w & 1) * 64, wn = (w >> 1) * 64;
  const int r15 = lane & 15, q4 = lane >> 4;
  const int rkey = (r15 >> 1) & 3;

  const int r0 = tid >> 2, jj = tid & 3;
  const int scol = (jj ^ ((r0 >> 1) & 3)) * 8;   // key same for r0+64 (64>>1 ≡ 0 mod 4)
  long ga0, ga1;
  if (isQ) { ga0 = (long)mb * 128 + r0; ga1 = ga0 + 64; }
  else {
    ga0 = (long)b * T_ + idx[b * T_ + s0 + r0];
    ga1 = (long)b * T_ + idx[b * T_ + s0 + r0 + 64];
  }
  const f16* pA0 = A + ga0 * K + scol;
  const f16* pA1 = A + ga1 * K + scol;
  const int ncol0 = isQ ? nb * 128 : C_ + (nb - 6) * 128;   // global qkv col base
  const f16* pB0 = Bt + (long)(ncol0 + r0) * K + scol;
  const f16* pB1 = pB0 + (long)64 * K;

  f32x4 acc[4][4];
#pragma unroll
  for (int i = 0; i < 4; i++)
#pragma unroll
    for (int j = 0; j < 4; j++) acc[i][j] = fzero4();

#define STAGE_QK(bufsel, kb) do {                                   \
  const int lb = (bufsel) * 4096;                                   \
  g2l16(pA0 + (kb), &lA[lb + tid * 8]);                             \
  g2l16(pA1 + (kb), &lA[lb + 2048 + tid * 8]);                      \
  g2l16(pB0 + (kb), &lB[lb + tid * 8]);                             \
  g2l16(pB1 + (kb), &lB[lb + 2048 + tid * 8]);                      \
} while (0)

#define COMPUTE_QK(bufsel) do {                                     \
  const int lb = (bufsel) * 4096;                                   \
  const int cofs = (q4 ^ rkey) * 8;                                 \
  f16x8 af[4], bfv[4];                                              \
  _Pragma("unroll")                                                 \
  for (int mi = 0; mi < 4; mi++)                                    \
    af[mi] = *(const f16x8*)&lA[lb + (wm + mi * 16 + r15) * 32 + cofs]; \
  _Pragma("unroll")                                                 \
  for (int ni = 0; ni < 4; ni++)                                    \
    bfv[ni] = *(const f16x8*)&lB[lb + (wn + ni * 16 + r15) * 32 + cofs]; \
  _Pragma("unroll")                                                 \
  for (int mi = 0; mi < 4; mi++)                                    \
    _Pragma("unroll")                                               \
    for (int ni = 0; ni < 4; ni++)                                  \
      acc[mi][ni] = __builtin_amdgcn_mfma_f32_16x16x32_f16(af[mi], bfv[ni], acc[mi][ni], 0, 0, 0); \
} while (0)

  STAGE_QK(0, 0);
  __syncthreads();

  int cur = 0;
  const int NT = K / 32;                 // 24
  for (int t = 0; t < NT - 1; t++) {
    STAGE_QK(cur ^ 1, (t + 1) * 32);
    COMPUTE_QK(cur);
    __syncthreads();
    cur ^= 1;
  }
  COMPUTE_QK(cur);

#undef STAGE_QK
#undef COMPUTE_QK

#pragma unroll
  for (int ni = 0; ni < 4; ni++) {
    const int gcol = ncol0 + wn + ni * 16 + r15;    // 0..2303
    const float bs = bias[gcol];
    if (isQ) {
#pragma unroll
      for (int mi = 0; mi < 4; mi++)
#pragma unroll
        for (int r = 0; r < 4; r++) {
          const long row = (long)mb * 128 + wm + mi * 16 + q4 * 4 + r;
          Qb[row * C_ + gcol] = (f16)(acc[mi][ni][r] + bs);
        }
    } else if (gcol < 2 * C_) {
      const int ocol = gcol - C_;
#pragma unroll
      for (int mi = 0; mi < 4; mi++)
#pragma unroll
        for (int r = 0; r < 4; r++) {
          const long row = (long)b * T_ + s0 + wm + mi * 16 + q4 * 4 + r;
          Kc[row * C_ + ocol] = (f16)(acc[mi][ni][r] + bs);
        }
    } else {
      // V transposed: Vtc[bh][d][slot]; 4 consecutive slots -> one f16x4 store
      const int vcol = gcol - 2 * C_;               // 0..767
      const int vh = vcol >> 6, d = vcol & 63;
      f16* dst = Vt + ((long)(b * H_ + vh) * D_ + d) * T_;
#pragma unroll
      for (int mi = 0; mi < 4; mi++) {
        const long slot = s0 + wm + mi * 16 + q4 * 4;
        f16x4 v4;
#pragma unroll
        for (int r = 0; r < 4; r++) v4[r] = (f16)(acc[mi][ni][r] + bs);
        *(f16x4*)&dst[slot] = v4;
      }
    }
  }
}

// ------- flash attention v2 (pinned 43-44.5us): g2l16-dbuf K/V staging, in-register
// P via cvt_pkrtz+permlane32_swap, setprio around MFMA, XCD swizzle. -------
__global__ __launch_bounds__(256, 4)
void attn_kernel(const f16* __restrict__ Qb, const f16* __restrict__ Kc,
                 const f16* __restrict__ vtc, const int* __restrict__ cnt,
                 f16* __restrict__ ctx) {
  __shared__ f16 Ks[2][64 * 64];
  __shared__ f16 Vs[2][64 * 64];
  __shared__ float Ls[4][32];
  const int tid = threadIdx.x, lane = tid & 63, w = tid >> 6;
  const int l31 = lane & 31, hh = lane >> 5;

  // bijective XCD swizzle: dispatch id g -> xcd g&7 handles 6 contiguous bh
  const int g = blockIdx.y * 16 + blockIdx.x;   // 0..767, dispatch order
  const int xcd = g & 7, local = g >> 3;        // 96 blocks per xcd
  const int bh = xcd * 6 + (local >> 4);        // 6 bh per xcd
  const int q0 = (local & 15) * 128;
  const int b = bh / H_, h = bh % H_;

  const f16* Qg = Qb + (long)(b * T_ + q0) * C_ + h * D_;
  const f16* Kbase = Kc + (long)b * T_ * C_ + h * D_;  // + slot*C_
  const f16* Vg = vtc + (long)bh * D_ * T_;            // [d][slot]
  const int nk = cnt[b];
  const int nkt = (nk + 63) >> 6;

  // Q frags direct from global, pre-scaled by 1/sqrt(D)*log2(e)
  const f16 qsc = (f16)0.18033688f;  // 0.125 * 1.44269504
  f16x8 bq[4];
#pragma unroll
  for (int j = 0; j < 4; j++) {
    f16x8 v = *(const f16x8*)(Qg + (long)(w * 32 + l31) * C_ + j * 16 + hh * 8);
#pragma unroll
    for (int e = 0; e < 8; e++) v[e] = v[e] * qsc;
    bq[j] = v;
  }

  // staging geometry: chunk c = w*128 + i*64 + lane (i=0,1); row r=c>>3, slot jj=c&7
  const int r_0 = w * 16 + (lane >> 3);        // i=0 row; i=1 row = r_0+8
  const int sc = ((lane & 7) ^ (r_0 & 7)) * 8; // source col, f16 units (same for i=0,1)
  const f16* Ksrc0 = Kbase + (long)r_0 * C_ + sc;
  const f16* Ksrc1 = Kbase + (long)(r_0 + 8) * C_ + sc;
  const f16* Vsrc0 = Vg + (long)r_0 * T_ + sc;
  const f16* Vsrc1 = Vg + (long)(r_0 + 8) * T_ + sc;
  const int ld0 = w * 1024 + lane * 8;         // f16 offset of chunk i=0
  const int ld1 = ld0 + 512;                   // i=1 (+64 chunks)

#define ATTN_STAGE(bs, kt) do {                                  \
    g2l16(Ksrc0 + (long)(kt) * C_, &Ks[bs][ld0]);                \
    g2l16(Ksrc1 + (long)(kt) * C_, &Ks[bs][ld1]);                \
    g2l16(Vsrc0 + (kt), &Vs[bs][ld0]);                           \
    g2l16(Vsrc1 + (kt), &Vs[bs][ld1]);                           \
  } while (0)

  float l_acc = 0.f;
  f32x16 O[2];
#pragma unroll
  for (int dt = 0; dt < 2; dt++)
#pragma unroll
    for (int r = 0; r < 16; r++) O[dt][r] = 0.f;

  const int swz = l31 & 7;  // read-side swizzle key (rows are 32-multiples + l31)

  ATTN_STAGE(0, 0);
  __syncthreads();

  int cur = 0;
  for (int t = 0; t < nkt; t++) {
    const int kt = t * 64;
    if (t + 1 < nkt) ATTN_STAGE(cur ^ 1, kt + 64);   // prefetch before compute

    u32x4 paw[4];
    const bool full = (kt + 64 <= nk);  // wave-uniform
#pragma unroll
    for (int t2 = 0; t2 < 2; t2++) {
      f32x16 acc;
      if (full) {
#pragma unroll
        for (int r = 0; r < 16; r++) acc[r] = 0.f;
      } else {
        const int kbase = kt + t2 * 32 + hh * 4;
#pragma unroll
        for (int g4 = 0; g4 < 4; g4++)
#pragma unroll
          for (int i = 0; i < 4; i++)
            acc[4 * g4 + i] = (kbase + 8 * g4 + i < nk) ? 0.f : -1e30f;
      }
      __builtin_amdgcn_s_setprio(1);
#pragma unroll
      for (int j = 0; j < 4; j++) {   // A=K[m=key=t2*32+l31][k=d chunk (j*2+hh)^swz]
        f16x8 ak = *(const f16x8*)&Ks[cur][(t2 * 32 + l31) * 64 + (((j * 2 + hh) ^ swz) << 3)];
        acc = __builtin_amdgcn_mfma_f32_32x32x16_f16(ak, bq[j], acc, 0, 0, 0);
      }
      __builtin_amdgcn_s_setprio(0);
      uint32_t wg[4], xg[4];
#pragma unroll
      for (int g4 = 0; g4 < 4; g4++) {
        const float p0 = __builtin_amdgcn_exp2f(acc[4 * g4 + 0]);
        const float p1 = __builtin_amdgcn_exp2f(acc[4 * g4 + 1]);
        const float p2 = __builtin_amdgcn_exp2f(acc[4 * g4 + 2]);
        const float p3 = __builtin_amdgcn_exp2f(acc[4 * g4 + 3]);
        l_acc += (p0 + p1) + (p2 + p3);
        wg[g4] = pk_u32(p0, p1);   // keys 8g+4hh+{0,1}
        xg[g4] = pk_u32(p2, p3);   // keys 8g+4hh+{2,3}
      }
#pragma unroll
      for (int jl = 0; jl < 2; jl++) {
        uint32_t w0 = wg[2 * jl], w2v = wg[2 * jl + 1];
        uint32_t w1 = xg[2 * jl], w3v = xg[2 * jl + 1];
        pl32swap(w0, w2v);
        pl32swap(w1, w3v);
        paw[2 * t2 + jl][0] = w0;  paw[2 * t2 + jl][1] = w1;
        paw[2 * t2 + jl][2] = w2v; paw[2 * t2 + jl][3] = w3v;
      }
    }

    // O += P V: A=P[q=l31][key], B=V[key][d=dt*32+l31] (Vs stores [d][key])
    __builtin_amdgcn_s_setprio(1);
#pragma unroll
    for (int j = 0; j < 4; j++) {
      const f16x8 pa = *(const f16x8*)&paw[j];
#pragma unroll
      for (int dt = 0; dt < 2; dt++) {
        const int vrow = dt * 32 + l31;
        f16x8 vb = *(const f16x8*)&Vs[cur][vrow * 64 + (((j * 2 + hh) ^ swz) << 3)];
        O[dt] = __builtin_amdgcn_mfma_f32_32x32x16_f16(pa, vb, O[dt], 0, 0, 0);
      }
    }
    __builtin_amdgcn_s_setprio(0);

    __syncthreads();   // drains prefetch (vmcnt 0) + all LDS reads before overwrite
    cur ^= 1;
  }
#undef ATTN_STAGE

  // l finalize: partner (xor 32) holds the complementary key subset for same q
  l_acc += __shfl_xor(l_acc, 32);
  asm volatile("s_waitcnt lgkmcnt(0)" ::: "memory");
  if (hh == 0) Ls[w][l31] = l_acc;
  asm volatile("s_waitcnt lgkmcnt(0)" ::: "memory");
#pragma unroll
  for (int g4 = 0; g4 < 4; g4++) {
    const f32x4 lv = *(const f32x4*)&Ls[w][g4 * 8 + hh * 4];  // broadcast
#pragma unroll
    for (int i = 0; i < 4; i++) {
      const float inv = 1.f / lv[i];
      const int row = b * T_ + q0 + w * 32 + g4 * 8 + hh * 4 + i;
#pragma unroll
      for (int dt = 0; dt < 2; dt++)
        ctx[(long)row * C_ + h * D_ + dt * 32 + l31] = (f16)(O[dt][4 * g4 + i] * inv);
    }
  }
}

extern "C" void kernel_launch(void* const* d_in, const int* in_sizes, int n_in,
                              void* d_out, int out_size, void* d_ws, size_t ws_size,
                              hipStream_t stream) {
  (void)in_sizes; (void)n_in; (void)out_size; (void)ws_size;
  const float* x    = (const float*)d_in[0];
  const int*   mask = (const int*)  d_in[1];
  const float* Wqkv = (const float*)d_in[2];
  const float* bqkv = (const float*)d_in[3];
  const float* Wo   = (const float*)d_in[4];
  const float* bo   = (const float*)d_in[5];
  float* out = (float*)d_out;

  char* ws = (char*)d_ws;
  const size_t OFF_WQKVT = 0;                         // 2304*768*2  = 3538944
  const size_t OFF_WOT   = OFF_WQKVT + 3538944;       // 768*768*2   = 1179648
  const size_t OFF_Q     = OFF_WOT + 1179648;         // 8192*768*2  = 12582912
  const size_t OFF_KC    = OFF_Q + 12582912;          // 4*2048*768*2= 12582912
  const size_t OFF_VT    = OFF_KC + 12582912;         // 48*64*2048*2= 12582912
  const size_t OFF_XH    = OFF_VT + 12582912;         // 8192*768*2  = 12582912 (xh, later ctx)
  const size_t OFF_IDX   = OFF_XH + 12582912;         // 4*2048*4    = 32768
  const size_t OFF_CNT   = OFF_IDX + 32768;           // 4*4
  f16* WqkvT = (f16*)(ws + OFF_WQKVT);
  f16* WoT   = (f16*)(ws + OFF_WOT);
  f16* Qb    = (f16*)(ws + OFF_Q);
  f16* Kc    = (f16*)(ws + OFF_KC);
  f16* Vtc   = (f16*)(ws + OFF_VT);
  f16* xh    = (f16*)(ws + OFF_XH);   // dead after QKV GEMM
  f16* ctx   = (f16*)(ws + OFF_XH);   // written by attn afterwards
  int* idx   = (int*)(ws + OFF_IDX);
  int* cnt   = (int*)(ws + OFF_CNT);

  prep_kernel<<<dim3(8452), 256, 0, stream>>>(Wqkv, WqkvT, Wo, WoT, x, xh, mask, idx, cnt);
  gemm_qkv128<<<dim3(18, 64), 256, 0, stream>>>(xh, WqkvT, bqkv, Qb, Kc, Vtc, idx, cnt);
  attn_kernel<<<dim3(16, 48), 256, 0, stream>>>(Qb, Kc, Vtc, cnt, ctx);
  gemm_bias_kernel<float><<<dim3(6, 64), 256, 0, stream>>>(ctx, WoT, bo, out, 768, 768);
}